// Round 16
// baseline (568.967 us; speedup 1.0000x reference)
//
#include <hip/hip_runtime.h>

#define SEQ   8192
#define VOCAB 128000
#define L     64
#define NCH   128   // SEQ / L

// ws layout (float offsets)
#define OFF_CMB    0        // CmbT[k][t] : [20][8192] fp32 combined, k-major
#define OFF_CVEC   163840   // cvecT[k][m][i] : [64][128][10]
#define OFF_AMAX   245760   // amax64[t] : 8192 x u64 packed (key<<32 | VOCAB-idx)
#define OFF_AMAX1  262144   // amax1[t] : 8192 x u32 sortable approx max
#define OFF_CNORM  278528   // ||c_t||_2 (augmented, incl. the 1.0) fp32
#define OFF_WMAX   286720   // max_v ||[W_v,b_v]||_2 as u32 bits (+pad)
#define OFF_C32    286784   // c32[t][32] bf16 (incl. 1.0 at k=20)
#define OFF_W32    417856   // W32[v][32] bf16 (incl. bias at k=20)
// total 2,465,856 floats = 9.86 MB

#define TBLK   16   // t-blocks of 512 t
#define VSLICE 50   // v-slices of 2560 v
#define CHUNKS 10   // 256-row chunks per slice
#define CCAP   2048 // candidate list capacity per block

typedef __attribute__((ext_vector_type(8))) short bf16x8;
typedef __attribute__((ext_vector_type(4))) float f32x4;

static __device__ inline unsigned short f2bf(float x) {
    unsigned u = __float_as_uint(x);
    u += 0x7FFF + ((u >> 16) & 1);          // RNE
    return (unsigned short)(u >> 16);
}
static __device__ inline unsigned sortable(float x) {
    unsigned u = __float_as_uint(x);
    return (u & 0x80000000u) ? ~u : (u | 0x80000000u);
}
static __device__ inline float unsortable(unsigned k) {
    unsigned u = (k & 0x80000000u) ? (k & 0x7FFFFFFFu) : ~k;
    return __uint_as_float(u);
}

// ---------------------------------------------------------------------------
// K1: gather embeddings -> CmbT rows 0..9; cvec; zero amax64/amax1/wmax.
// ---------------------------------------------------------------------------
__global__ void k_embed(const int* __restrict__ ix, const float* __restrict__ emb,
                        const float* __restrict__ Wih, const float* __restrict__ bih,
                        float* __restrict__ ws) {
    int t = blockIdx.x * blockDim.x + threadIdx.x;
    if (t >= SEQ) return;
    ((unsigned long long*)(ws + OFF_AMAX))[t] = 0ULL;
    ((unsigned*)(ws + OFF_AMAX1))[t] = 0u;
    if (t == 0) ((unsigned*)(ws + OFF_WMAX))[0] = 0u;

    int id = ix[t];
    float w[10];
    const float2* ep = (const float2*)(emb + (long long)id * 10);
#pragma unroll
    for (int j = 0; j < 5; j++) ((float2*)w)[j] = ep[j];
#pragma unroll
    for (int j = 0; j < 10; j++) ws[OFF_CMB + j * SEQ + t] = w[j];

    int m = t >> 6, k = t & 63;
    float* cv = ws + OFF_CVEC + (k * NCH + m) * 10;
#pragma unroll
    for (int i = 0; i < 10; i++) {
        float s = bih[i];
#pragma unroll
        for (int j = 0; j < 10; j++) s += Wih[i * 20 + j] * w[j];
        cv[i] = s;
    }
}

// ---------------------------------------------------------------------------
// K2: pack [W_v, bias_v] -> bf16 [v][32] (k=20 is bias, 21..31 zero) and
// global max augmented row-norm (wave-reduced: 1 atomic per wave, not 64).
// ---------------------------------------------------------------------------
__global__ void k_pack_w(const float* __restrict__ Wio, const float* __restrict__ bio,
                         float* __restrict__ ws) {
    int v = blockIdx.x * blockDim.x + threadIdx.x;
    if (v >= VOCAB) return;
    float w[20];
    const float4* r = (const float4*)(Wio + (long long)v * 20);
#pragma unroll
    for (int q = 0; q < 5; q++) ((float4*)w)[q] = r[q];
    float b = bio[v];
    float n2 = b * b;
#pragma unroll
    for (int k = 0; k < 20; k++) n2 += w[k] * w[k];
    float nrm = sqrtf(n2);
    // wave-level max reduce, then one atomic per wave
    for (int off = 1; off < 64; off <<= 1)
        nrm = fmaxf(nrm, __shfl_xor(nrm, off));
    if ((threadIdx.x & 63) == 0)
        atomicMax((unsigned*)(ws + OFF_WMAX), __float_as_uint(nrm));

    unsigned short h[32];
#pragma unroll
    for (int k = 0; k < 20; k++) h[k] = f2bf(w[k]);
    h[20] = f2bf(b);
#pragma unroll
    for (int k = 21; k < 32; k++) h[k] = 0;
    uint4* dst = (uint4*)((unsigned short*)(ws + OFF_W32));
#pragma unroll
    for (int i = 0; i < 4; i++) {
        uint4 u;
        u.x = (unsigned)h[8*i+0] | ((unsigned)h[8*i+1] << 16);
        u.y = (unsigned)h[8*i+2] | ((unsigned)h[8*i+3] << 16);
        u.z = (unsigned)h[8*i+4] | ((unsigned)h[8*i+5] << 16);
        u.w = (unsigned)h[8*i+6] | ((unsigned)h[8*i+7] << 16);
        dst[v * 4 + i] = u;
    }
}

// ---------------------------------------------------------------------------
// K3: blocked scan of h_{t+1} = A h_t + c_t -> CmbT rows 10..19.
// ---------------------------------------------------------------------------
__global__ void k_scan(const float* __restrict__ Wih, float* __restrict__ ws) {
    __shared__ float P[100], Q[100];
    __shared__ float Dl[NCH][10];
    __shared__ float Hst[NCH][10];
    __shared__ float Hl[10];
    int tid = threadIdx.x;

    float Ar[10][10];
#pragma unroll
    for (int i = 0; i < 10; i++)
#pragma unroll
        for (int j = 0; j < 10; j++) Ar[i][j] = Wih[i * 20 + 10 + j];

    {   // phase A
        int m = tid;
        float h[10];
#pragma unroll
        for (int i = 0; i < 10; i++) h[i] = 0.f;
        const float* cvb = ws + OFF_CVEC;
        float2 buf[5];
        {
            const float2* cp = (const float2*)(cvb + m * 10);
#pragma unroll
            for (int j = 0; j < 5; j++) buf[j] = cp[j];
        }
        for (int k = 0; k < L; k++) {
            float cc[10];
#pragma unroll
            for (int j = 0; j < 5; j++) { cc[2*j] = buf[j].x; cc[2*j+1] = buf[j].y; }
            if (k + 1 < L) {
                const float2* cp = (const float2*)(cvb + ((k + 1) * NCH + m) * 10);
#pragma unroll
                for (int j = 0; j < 5; j++) buf[j] = cp[j];
            }
            float nh[10];
#pragma unroll
            for (int i = 0; i < 10; i++) {
                float s = cc[i];
#pragma unroll
                for (int j = 0; j < 10; j++) s += Ar[i][j] * h[j];
                nh[i] = s;
            }
#pragma unroll
            for (int i = 0; i < 10; i++) h[i] = nh[i];
        }
#pragma unroll
        for (int i = 0; i < 10; i++) Dl[m][i] = h[i];
    }

    if (tid < 100) P[tid] = Wih[(tid / 10) * 20 + 10 + (tid % 10)];
    __syncthreads();
    for (int it = 0; it < 6; it++) {
        if (tid < 100) {
            int i = tid / 10, j = tid % 10;
            float s = 0.f;
#pragma unroll
            for (int k = 0; k < 10; k++) s += P[i * 10 + k] * P[k * 10 + j];
            Q[tid] = s;
        }
        __syncthreads();
        if (tid < 100) P[tid] = Q[tid];
        __syncthreads();
    }

    if (tid < 10) Hl[tid] = 0.f;
    __syncthreads();
    if (tid < 10) {
        int i = tid;
        float a64[10];
#pragma unroll
        for (int j = 0; j < 10; j++) a64[j] = P[i * 10 + j];
        float hc = 0.f;
        for (int m = 0; m < NCH; m++) {
            Hst[m][i] = hc;
            float s = Dl[m][i];
#pragma unroll
            for (int j = 0; j < 10; j++) s += a64[j] * Hl[j];
            Hl[i] = s;
            hc = s;
        }
    }
    __syncthreads();

    {   // phase C
        int m = tid;
        float h[10];
#pragma unroll
        for (int i = 0; i < 10; i++) h[i] = Hst[m][i];
        const float* cvb = ws + OFF_CVEC;
        float2 buf[5];
        {
            const float2* cp = (const float2*)(cvb + m * 10);
#pragma unroll
            for (int j = 0; j < 5; j++) buf[j] = cp[j];
        }
        for (int k = 0; k < L; k++) {
            int tg = m * 64 + k;
            float cc[10];
#pragma unroll
            for (int j = 0; j < 5; j++) { cc[2*j] = buf[j].x; cc[2*j+1] = buf[j].y; }
            if (k + 1 < L) {
                const float2* cp = (const float2*)(cvb + ((k + 1) * NCH + m) * 10);
#pragma unroll
                for (int j = 0; j < 5; j++) buf[j] = cp[j];
            }
#pragma unroll
            for (int i = 0; i < 10; i++) ws[OFF_CMB + (10 + i) * SEQ + tg] = h[i];
            float nh[10];
#pragma unroll
            for (int i = 0; i < 10; i++) {
                float s = cc[i];
#pragma unroll
                for (int j = 0; j < 10; j++) s += Ar[i][j] * h[j];
                nh[i] = s;
            }
#pragma unroll
            for (int i = 0; i < 10; i++) h[i] = nh[i];
        }
    }
}

// ---------------------------------------------------------------------------
// K4: pack c -> bf16 [t][32] (k=20 is 1.0) + augmented ||c_t||_2.
// ---------------------------------------------------------------------------
__global__ void k_pack_c(float* __restrict__ ws) {
    int t = blockIdx.x * blockDim.x + threadIdx.x;
    if (t >= SEQ) return;
    float c[20];
#pragma unroll
    for (int k = 0; k < 20; k++) c[k] = ws[OFF_CMB + k * SEQ + t];
    float n2 = 1.0f;                       // augmented (the 1.0 for bias)
#pragma unroll
    for (int k = 0; k < 20; k++) n2 += c[k] * c[k];
    ws[OFF_CNORM + t] = sqrtf(n2);

    unsigned short h[32];
#pragma unroll
    for (int k = 0; k < 20; k++) h[k] = f2bf(c[k]);
    h[20] = f2bf(1.0f);                    // exact
#pragma unroll
    for (int k = 21; k < 32; k++) h[k] = 0;
    uint4* dst = (uint4*)((unsigned short*)(ws + OFF_C32));
#pragma unroll
    for (int i = 0; i < 4; i++) {
        uint4 u;
        u.x = (unsigned)h[8*i+0] | ((unsigned)h[8*i+1] << 16);
        u.y = (unsigned)h[8*i+2] | ((unsigned)h[8*i+3] << 16);
        u.z = (unsigned)h[8*i+4] | ((unsigned)h[8*i+5] << 16);
        u.w = (unsigned)h[8*i+6] | ((unsigned)h[8*i+7] << 16);
        dst[t * 4 + i] = u;
    }
}

// ---------------------------------------------------------------------------
// K5 (pass 1): approx max via MFMA. Bias folded into K (k=20) -> acc input
// is a loop-invariant zero (no per-MFMA init). vt processed in PAIRS with
// run = fmax(run, fmax(d0,d1)) -> v_max3, 2 VALU/MFMA (was ~8).
// ---------------------------------------------------------------------------
__global__ __launch_bounds__(256)
void k_max1(const float* __restrict__ ws, unsigned* __restrict__ amax1) {
    __shared__ unsigned short WlS[256 * 32];   // 16 KB, 64 B pitch

    int tid = threadIdx.x;
    int lane = tid & 63, wid = tid >> 6, quad = lane >> 4, col = lane & 15;
    int tb  = blockIdx.x / VSLICE;
    int sl  = blockIdx.x % VSLICE;
    int t0w = tb * 512 + wid * 128;
    int v0s = sl * 2560;

    const unsigned short* c32 = (const unsigned short*)(ws + OFF_C32);
    const uint4* W32g = (const uint4*)((const unsigned short*)(ws + OFF_W32));

    bf16x8 a[8];
#pragma unroll
    for (int tt = 0; tt < 8; tt++)
        a[tt] = *(const bf16x8*)(c32 + (t0w + tt * 16 + col) * 32 + quad * 8);

    const f32x4 zero = {0.f, 0.f, 0.f, 0.f};
    float run[8][4];
#pragma unroll
    for (int tt = 0; tt < 8; tt++)
#pragma unroll
        for (int g = 0; g < 4; g++) run[tt][g] = -3.4e38f;

    for (int ch = 0; ch < CHUNKS; ch++) {
        __syncthreads();
        int vb = v0s + ch * 256;
#pragma unroll
        for (int i = 0; i < 4; i++)
            ((uint4*)WlS)[tid + 256 * i] = W32g[vb * 4 + tid + 256 * i];
        __syncthreads();

        for (int vt = 0; vt < 16; vt += 2) {
            bf16x8 b0 = *(const bf16x8*)(WlS + (vt * 16 + col) * 32 + quad * 8);
            bf16x8 b1 = *(const bf16x8*)(WlS + ((vt + 1) * 16 + col) * 32 + quad * 8);
#pragma unroll
            for (int tt = 0; tt < 8; tt++) {
                f32x4 d0 = __builtin_amdgcn_mfma_f32_16x16x32_bf16(a[tt], b0, zero, 0, 0, 0);
                f32x4 d1 = __builtin_amdgcn_mfma_f32_16x16x32_bf16(a[tt], b1, zero, 0, 0, 0);
#pragma unroll
                for (int g = 0; g < 4; g++)
                    run[tt][g] = fmaxf(run[tt][g], fmaxf(d0[g], d1[g]));  // v_max3
            }
        }
    }

    // reduce over the 16 v-columns, then atomic per t
#pragma unroll
    for (int tt = 0; tt < 8; tt++)
#pragma unroll
        for (int g = 0; g < 4; g++) {
            float r = run[tt][g];
            for (int off = 1; off < 16; off <<= 1)
                r = fmaxf(r, __shfl_xor(r, off));
            if (col == 0)
                atomicMax(&amax1[t0w + tt * 16 + quad * 4 + g], sortable(r));
        }
}

// ---------------------------------------------------------------------------
// K6 (pass 2): candidate pass. Threshold computed inline from amax1 (folds
// the old k_thresh). Detection: 7 VALU per 2 MFMAs (pairwise max + max-tree
// + 1 cmp); rare hit path appends (t<<17|v) to LDS list; exact fp32 fixup
// in the block epilogue (packed-u64 atomicMax = exact jnp.argmax).
// ---------------------------------------------------------------------------
__global__ __launch_bounds__(256)
void k_cand(const float* __restrict__ ws, const float* __restrict__ Wio,
            const float* __restrict__ bio, const unsigned* __restrict__ amax1,
            unsigned long long* __restrict__ amax) {
    __shared__ unsigned short WlS[256 * 32];   // 16 KB
    __shared__ unsigned cand[CCAP];            // 8 KB
    __shared__ unsigned cnt;

    int tid = threadIdx.x;
    int lane = tid & 63, wid = tid >> 6, quad = lane >> 4, col = lane & 15;
    int tb  = blockIdx.x / VSLICE;
    int sl  = blockIdx.x % VSLICE;
    int t0w = tb * 512 + wid * 128;
    int v0s = sl * 2560;
    if (tid == 0) cnt = 0;

    const unsigned short* c32 = (const unsigned short*)(ws + OFF_C32);
    const uint4* W32g = (const uint4*)((const unsigned short*)(ws + OFF_W32));
    float wmax = __uint_as_float(((const unsigned*)(ws + OFF_WMAX))[0]);

    bf16x8 a[8];
    float thr[8][4], thrmin[8];
#pragma unroll
    for (int tt = 0; tt < 8; tt++) {
        a[tt] = *(const bf16x8*)(c32 + (t0w + tt * 16 + col) * 32 + quad * 8);
        float mn = 3.4e38f;
#pragma unroll
        for (int g = 0; g < 4; g++) {
            int t = t0w + tt * 16 + quad * 4 + g;
            float maxap = unsortable(amax1[t]);
            thr[tt][g] = maxap - (0.04f * ws[OFF_CNORM + t] * wmax + 1e-5f);
            mn = fminf(mn, thr[tt][g]);
        }
        thrmin[tt] = mn;
    }

    const f32x4 zero = {0.f, 0.f, 0.f, 0.f};

    for (int ch = 0; ch < CHUNKS; ch++) {
        __syncthreads();
        int vb = v0s + ch * 256;
#pragma unroll
        for (int i = 0; i < 4; i++)
            ((uint4*)WlS)[tid + 256 * i] = W32g[vb * 4 + tid + 256 * i];
        __syncthreads();

        for (int vt = 0; vt < 16; vt += 2) {
            bf16x8 b0 = *(const bf16x8*)(WlS + (vt * 16 + col) * 32 + quad * 8);
            bf16x8 b1 = *(const bf16x8*)(WlS + ((vt + 1) * 16 + col) * 32 + quad * 8);
            int v0 = vb + vt * 16 + col;
#pragma unroll
            for (int tt = 0; tt < 8; tt++) {
                f32x4 d0 = __builtin_amdgcn_mfma_f32_16x16x32_bf16(a[tt], b0, zero, 0, 0, 0);
                f32x4 d1 = __builtin_amdgcn_mfma_f32_16x16x32_bf16(a[tt], b1, zero, 0, 0, 0);
                float m0 = fmaxf(d0[0], d1[0]);
                float m1 = fmaxf(d0[1], d1[1]);
                float m2 = fmaxf(d0[2], d1[2]);
                float m3 = fmaxf(d0[3], d1[3]);
                float hm = fmaxf(fmaxf(m0, m1), fmaxf(m2, m3));
                if (hm >= thrmin[tt]) {
#pragma unroll
                    for (int g = 0; g < 4; g++) {
                        unsigned t = (unsigned)(t0w + tt * 16 + quad * 4 + g);
                        if (d0[g] >= thr[tt][g]) {
                            unsigned idx = atomicAdd(&cnt, 1u);
                            if (idx < CCAP) cand[idx] = (t << 17) | (unsigned)v0;
                        }
                        if (d1[g] >= thr[tt][g]) {
                            unsigned idx = atomicAdd(&cnt, 1u);
                            if (idx < CCAP) cand[idx] = (t << 17) | (unsigned)(v0 + 16);
                        }
                    }
                }
            }
        }
    }

    __syncthreads();
    // epilogue: exact fp32 re-evaluation of candidates
    unsigned n = cnt < CCAP ? cnt : CCAP;
    const float* cmb = ws + OFF_CMB;
    for (unsigned i = tid; i < n; i += 256) {
        unsigned e = cand[i];
        int t = (int)(e >> 17);
        int v = (int)(e & 0x1FFFFu);
        const float* wr = Wio + (long long)v * 20;
        float ex = bio[v];
#pragma unroll
        for (int k = 0; k < 20; k++)
            ex = fmaf(wr[k], cmb[k * SEQ + t], ex);
        unsigned key = sortable(ex);
        unsigned long long packed =
            ((unsigned long long)key << 32) | (unsigned)(VOCAB - v);
        atomicMax(&amax[t], packed);
    }
}

// ---------------------------------------------------------------------------
// K7: unpack argmax -> float index
// ---------------------------------------------------------------------------
__global__ void k_out(const unsigned long long* __restrict__ amax,
                      float* __restrict__ out) {
    int t = blockIdx.x * blockDim.x + threadIdx.x;
    if (t >= SEQ) return;
    unsigned long long p = amax[t];
    int idx = VOCAB - (int)(p & 0xFFFFFFFFu);
    out[t] = (float)idx;
}

// ---------------------------------------------------------------------------
extern "C" void kernel_launch(void* const* d_in, const int* in_sizes, int n_in,
                              void* d_out, int out_size, void* d_ws, size_t ws_size,
                              hipStream_t stream) {
    (void)in_sizes; (void)n_in; (void)out_size; (void)ws_size;
    const int*   ix  = (const int*)d_in[0];
    const float* emb = (const float*)d_in[1];
    const float* Wih = (const float*)d_in[2];
    const float* bih = (const float*)d_in[3];
    const float* Wio = (const float*)d_in[4];
    const float* bio = (const float*)d_in[5];
    float* out = (float*)d_out;
    float* ws  = (float*)d_ws;
    unsigned long long* amax = (unsigned long long*)(ws + OFF_AMAX);
    unsigned* amax1 = (unsigned*)(ws + OFF_AMAX1);

    hipLaunchKernelGGL(k_embed,  dim3(SEQ / 256),     dim3(256), 0, stream, ix, emb, Wih, bih, ws);
    hipLaunchKernelGGL(k_pack_w, dim3(VOCAB / 256),   dim3(256), 0, stream, Wio, bio, ws);
    hipLaunchKernelGGL(k_scan,   dim3(1),             dim3(128), 0, stream, Wih, ws);
    hipLaunchKernelGGL(k_pack_c, dim3(SEQ / 256),     dim3(256), 0, stream, ws);
    hipLaunchKernelGGL(k_max1,   dim3(TBLK * VSLICE), dim3(256), 0, stream, ws, amax1);
    hipLaunchKernelGGL(k_cand,   dim3(TBLK * VSLICE), dim3(256), 0, stream, ws, Wio, bio, amax1, amax);
    hipLaunchKernelGGL(k_out,    dim3(SEQ / 256),     dim3(256), 0, stream, amax, out);
}

// Round 17
// 415.579 us; speedup vs baseline: 1.3691x; 1.3691x over previous
//
#include <hip/hip_runtime.h>

#define SEQ   8192
#define VOCAB 128000
#define L     64
#define NCH   128   // SEQ / L

// ws layout (float offsets)
#define OFF_CMB    0        // CmbT[k][t] : [20][8192] fp32 combined, k-major
#define OFF_CVEC   163840   // cvecT[k][m][i] : [64][128][10]
#define OFF_AMAX   245760   // amax64[t] : 8192 x u64 packed
#define OFF_AMAX1  262144   // amax1[t] : 8192 x u32 sortable approx max
#define OFF_CNORM  270336   // ||c_t||_2 augmented
#define OFF_WPART  278528   // per-block W-norm partials (500)
#define OFF_WMAX   279040   // final wmax (float)
#define OFF_C32    279104   // c32[t][32] bf16 (131072 floats)
#define OFF_W32    410176   // W32[v][32] bf16 (2048000 floats)
// total 2,458,176 floats = 9.83 MB

#define TBLK   16    // t-blocks of 512 t
#define VSLICE 100   // v-slices of 1280 v
#define CHUNKS 5     // 256-row chunks per slice
#define CCAP   2048

typedef __attribute__((ext_vector_type(8))) short bf16x8;
typedef __attribute__((ext_vector_type(4))) float f32x4;

static __device__ inline unsigned short f2bf(float x) {
    unsigned u = __float_as_uint(x);
    u += 0x7FFF + ((u >> 16) & 1);          // RNE
    return (unsigned short)(u >> 16);
}
static __device__ inline unsigned sortable(float x) {
    unsigned u = __float_as_uint(x);
    return (u & 0x80000000u) ? ~u : (u | 0x80000000u);
}
static __device__ inline float unsortable(unsigned k) {
    unsigned u = (k & 0x80000000u) ? (k & 0x7FFFFFFFu) : ~k;
    return __uint_as_float(u);
}

// ---------------------------------------------------------------------------
// K1 (k_prep): blocks 0..31 = embed (+ zero amax/amax1); blocks 32..531 =
// pack [W_v,b_v] -> bf16[v][32] + per-block augmented-norm partial (no
// atomics, no init ordering hazard).
// ---------------------------------------------------------------------------
__global__ void k_prep(const int* __restrict__ ix, const float* __restrict__ emb,
                       const float* __restrict__ Wih, const float* __restrict__ bih,
                       const float* __restrict__ Wio, const float* __restrict__ bio,
                       float* __restrict__ ws) {
    int b = blockIdx.x;
    int tid = threadIdx.x;
    if (b < 32) {
        int t = b * 256 + tid;
        ((unsigned long long*)(ws + OFF_AMAX))[t] = 0ULL;
        ((unsigned*)(ws + OFF_AMAX1))[t] = 0u;

        int id = ix[t];
        float w[10];
        const float2* ep = (const float2*)(emb + (long long)id * 10);
#pragma unroll
        for (int j = 0; j < 5; j++) ((float2*)w)[j] = ep[j];
#pragma unroll
        for (int j = 0; j < 10; j++) ws[OFF_CMB + j * SEQ + t] = w[j];

        int m = t >> 6, k = t & 63;
        float* cv = ws + OFF_CVEC + (k * NCH + m) * 10;
#pragma unroll
        for (int i = 0; i < 10; i++) {
            float s = bih[i];
#pragma unroll
            for (int j = 0; j < 10; j++) s += Wih[i * 20 + j] * w[j];
            cv[i] = s;
        }
    } else {
        __shared__ float red[4];
        int bs = b - 32;
        int v = bs * 256 + tid;
        float w[20];
        const float4* r = (const float4*)(Wio + (long long)v * 20);
#pragma unroll
        for (int q = 0; q < 5; q++) ((float4*)w)[q] = r[q];
        float bv = bio[v];
        float n2 = bv * bv;
#pragma unroll
        for (int k = 0; k < 20; k++) n2 += w[k] * w[k];
        float nrm = sqrtf(n2);
        for (int off = 1; off < 64; off <<= 1)
            nrm = fmaxf(nrm, __shfl_xor(nrm, off));
        if ((tid & 63) == 0) red[tid >> 6] = nrm;
        __syncthreads();
        if (tid == 0)
            ws[OFF_WPART + bs] = fmaxf(fmaxf(red[0], red[1]), fmaxf(red[2], red[3]));

        unsigned short h[32];
#pragma unroll
        for (int k = 0; k < 20; k++) h[k] = f2bf(w[k]);
        h[20] = f2bf(bv);
#pragma unroll
        for (int k = 21; k < 32; k++) h[k] = 0;
        uint4* dst = (uint4*)((unsigned short*)(ws + OFF_W32));
#pragma unroll
        for (int i = 0; i < 4; i++) {
            uint4 u;
            u.x = (unsigned)h[8*i+0] | ((unsigned)h[8*i+1] << 16);
            u.y = (unsigned)h[8*i+2] | ((unsigned)h[8*i+3] << 16);
            u.z = (unsigned)h[8*i+4] | ((unsigned)h[8*i+5] << 16);
            u.w = (unsigned)h[8*i+6] | ((unsigned)h[8*i+7] << 16);
            dst[v * 4 + i] = u;
        }
    }
}

// ---------------------------------------------------------------------------
// K2: blocked scan of h_{t+1} = A h_t + c_t -> CmbT rows 10..19.
// ---------------------------------------------------------------------------
__global__ void k_scan(const float* __restrict__ Wih, float* __restrict__ ws) {
    __shared__ float P[100], Q[100];
    __shared__ float Dl[NCH][10];
    __shared__ float Hst[NCH][10];
    __shared__ float Hl[10];
    int tid = threadIdx.x;

    float Ar[10][10];
#pragma unroll
    for (int i = 0; i < 10; i++)
#pragma unroll
        for (int j = 0; j < 10; j++) Ar[i][j] = Wih[i * 20 + 10 + j];

    {   // phase A
        int m = tid;
        float h[10];
#pragma unroll
        for (int i = 0; i < 10; i++) h[i] = 0.f;
        const float* cvb = ws + OFF_CVEC;
        float2 buf[5];
        {
            const float2* cp = (const float2*)(cvb + m * 10);
#pragma unroll
            for (int j = 0; j < 5; j++) buf[j] = cp[j];
        }
        for (int k = 0; k < L; k++) {
            float cc[10];
#pragma unroll
            for (int j = 0; j < 5; j++) { cc[2*j] = buf[j].x; cc[2*j+1] = buf[j].y; }
            if (k + 1 < L) {
                const float2* cp = (const float2*)(cvb + ((k + 1) * NCH + m) * 10);
#pragma unroll
                for (int j = 0; j < 5; j++) buf[j] = cp[j];
            }
            float nh[10];
#pragma unroll
            for (int i = 0; i < 10; i++) {
                float s = cc[i];
#pragma unroll
                for (int j = 0; j < 10; j++) s += Ar[i][j] * h[j];
                nh[i] = s;
            }
#pragma unroll
            for (int i = 0; i < 10; i++) h[i] = nh[i];
        }
#pragma unroll
        for (int i = 0; i < 10; i++) Dl[m][i] = h[i];
    }

    if (tid < 100) P[tid] = Wih[(tid / 10) * 20 + 10 + (tid % 10)];
    __syncthreads();
    for (int it = 0; it < 6; it++) {
        if (tid < 100) {
            int i = tid / 10, j = tid % 10;
            float s = 0.f;
#pragma unroll
            for (int k = 0; k < 10; k++) s += P[i * 10 + k] * P[k * 10 + j];
            Q[tid] = s;
        }
        __syncthreads();
        if (tid < 100) P[tid] = Q[tid];
        __syncthreads();
    }

    if (tid < 10) Hl[tid] = 0.f;
    __syncthreads();
    if (tid < 10) {
        int i = tid;
        float a64[10];
#pragma unroll
        for (int j = 0; j < 10; j++) a64[j] = P[i * 10 + j];
        float hc = 0.f;
        for (int m = 0; m < NCH; m++) {
            Hst[m][i] = hc;
            float s = Dl[m][i];
#pragma unroll
            for (int j = 0; j < 10; j++) s += a64[j] * Hl[j];
            Hl[i] = s;
            hc = s;
        }
    }
    __syncthreads();

    {   // phase C
        int m = tid;
        float h[10];
#pragma unroll
        for (int i = 0; i < 10; i++) h[i] = Hst[m][i];
        const float* cvb = ws + OFF_CVEC;
        float2 buf[5];
        {
            const float2* cp = (const float2*)(cvb + m * 10);
#pragma unroll
            for (int j = 0; j < 5; j++) buf[j] = cp[j];
        }
        for (int k = 0; k < L; k++) {
            int tg = m * 64 + k;
            float cc[10];
#pragma unroll
            for (int j = 0; j < 5; j++) { cc[2*j] = buf[j].x; cc[2*j+1] = buf[j].y; }
            if (k + 1 < L) {
                const float2* cp = (const float2*)(cvb + ((k + 1) * NCH + m) * 10);
#pragma unroll
                for (int j = 0; j < 5; j++) buf[j] = cp[j];
            }
#pragma unroll
            for (int i = 0; i < 10; i++) ws[OFF_CMB + (10 + i) * SEQ + tg] = h[i];
            float nh[10];
#pragma unroll
            for (int i = 0; i < 10; i++) {
                float s = cc[i];
#pragma unroll
                for (int j = 0; j < 10; j++) s += Ar[i][j] * h[j];
                nh[i] = s;
            }
#pragma unroll
            for (int i = 0; i < 10; i++) h[i] = nh[i];
        }
    }
}

// ---------------------------------------------------------------------------
// K3: blocks 0..31 pack c -> bf16[t][32] (k=20 is 1.0) + augmented norm;
// block 32 reduces the 500 W-norm partials -> wmax (stream-ordered, race-free).
// ---------------------------------------------------------------------------
__global__ void k_pack_c(float* __restrict__ ws) {
    int b = blockIdx.x;
    int tid = threadIdx.x;
    if (b == 32) {
        __shared__ float red[4];
        float m = 0.f;
        for (int i = tid; i < 500; i += 256) m = fmaxf(m, ws[OFF_WPART + i]);
        for (int off = 1; off < 64; off <<= 1)
            m = fmaxf(m, __shfl_xor(m, off));
        if ((tid & 63) == 0) red[tid >> 6] = m;
        __syncthreads();
        if (tid == 0)
            ws[OFF_WMAX] = fmaxf(fmaxf(red[0], red[1]), fmaxf(red[2], red[3]));
        return;
    }
    int t = b * 256 + tid;
    float c[20];
#pragma unroll
    for (int k = 0; k < 20; k++) c[k] = ws[OFF_CMB + k * SEQ + t];
    float n2 = 1.0f;
#pragma unroll
    for (int k = 0; k < 20; k++) n2 += c[k] * c[k];
    ws[OFF_CNORM + t] = sqrtf(n2);

    unsigned short h[32];
#pragma unroll
    for (int k = 0; k < 20; k++) h[k] = f2bf(c[k]);
    h[20] = f2bf(1.0f);
#pragma unroll
    for (int k = 21; k < 32; k++) h[k] = 0;
    uint4* dst = (uint4*)((unsigned short*)(ws + OFF_C32));
#pragma unroll
    for (int i = 0; i < 4; i++) {
        uint4 u;
        u.x = (unsigned)h[8*i+0] | ((unsigned)h[8*i+1] << 16);
        u.y = (unsigned)h[8*i+2] | ((unsigned)h[8*i+3] << 16);
        u.z = (unsigned)h[8*i+4] | ((unsigned)h[8*i+5] << 16);
        u.w = (unsigned)h[8*i+6] | ((unsigned)h[8*i+7] << 16);
        dst[t * 4 + i] = u;
    }
}

// ---------------------------------------------------------------------------
// K4 (pass 1): approx max via MFMA. Grid 1600 = 16 t-blocks x 100 v-slices
// (1280 v = 5 chunks). launch_bounds(256,2) -> 128 VGPRs (shuttle-free; a[]
// may live in AGPRs, which MFMA reads natively). Bias folded into K (k=20).
// ---------------------------------------------------------------------------
__global__ __launch_bounds__(256, 2)
void k_max1(const float* __restrict__ ws, unsigned* __restrict__ amax1) {
    __shared__ uint4 Wl4[1024];   // 16 KB, 64 B per v-row

    int tid = threadIdx.x;
    int lane = tid & 63, wid = tid >> 6, quad = lane >> 4, col = lane & 15;
    int tb  = blockIdx.x / VSLICE;
    int sl  = blockIdx.x % VSLICE;
    int t0w = tb * 512 + wid * 128;
    int v0s = sl * 1280;

    const unsigned short* c32 = (const unsigned short*)(ws + OFF_C32);
    const uint4* W32g = (const uint4*)((const unsigned short*)(ws + OFF_W32));
    const unsigned short* WlS = (const unsigned short*)Wl4;

    bf16x8 a[8];
#pragma unroll
    for (int tt = 0; tt < 8; tt++)
        a[tt] = *(const bf16x8*)(c32 + (t0w + tt * 16 + col) * 32 + quad * 8);

    const f32x4 zero = {0.f, 0.f, 0.f, 0.f};
    float run[8][4];
#pragma unroll
    for (int tt = 0; tt < 8; tt++)
#pragma unroll
        for (int g = 0; g < 4; g++) run[tt][g] = -3.4e38f;

    for (int ch = 0; ch < CHUNKS; ch++) {
        __syncthreads();
        int vb = v0s + ch * 256;
#pragma unroll
        for (int i = 0; i < 4; i++)
            Wl4[tid + 256 * i] = W32g[vb * 4 + tid + 256 * i];
        __syncthreads();

        for (int vt = 0; vt < 16; vt += 2) {
            bf16x8 b0 = *(const bf16x8*)(WlS + (vt * 16 + col) * 32 + quad * 8);
            bf16x8 b1 = *(const bf16x8*)(WlS + ((vt + 1) * 16 + col) * 32 + quad * 8);
#pragma unroll
            for (int tt = 0; tt < 8; tt++) {
                f32x4 d0 = __builtin_amdgcn_mfma_f32_16x16x32_bf16(a[tt], b0, zero, 0, 0, 0);
                f32x4 d1 = __builtin_amdgcn_mfma_f32_16x16x32_bf16(a[tt], b1, zero, 0, 0, 0);
#pragma unroll
                for (int g = 0; g < 4; g++)
                    run[tt][g] = fmaxf(run[tt][g], fmaxf(d0[g], d1[g]));
            }
        }
    }

#pragma unroll
    for (int tt = 0; tt < 8; tt++)
#pragma unroll
        for (int g = 0; g < 4; g++) {
            float r = run[tt][g];
            for (int off = 1; off < 16; off <<= 1)
                r = fmaxf(r, __shfl_xor(r, off));
            if (col == 0)
                atomicMax(&amax1[t0w + tt * 16 + quad * 4 + g], sortable(r));
        }
}

// ---------------------------------------------------------------------------
// K5 (pass 2): candidate pass + inline threshold + LDS candidate list +
// exact fp32 epilogue (packed-u64 atomicMax = exact jnp.argmax semantics).
// ---------------------------------------------------------------------------
__global__ __launch_bounds__(256, 2)
void k_cand(const float* __restrict__ ws, const float* __restrict__ Wio,
            const float* __restrict__ bio, const unsigned* __restrict__ amax1,
            unsigned long long* __restrict__ amax) {
    __shared__ uint4 Wl4[1024];   // 16 KB
    __shared__ unsigned cand[CCAP];
    __shared__ unsigned cnt;

    int tid = threadIdx.x;
    int lane = tid & 63, wid = tid >> 6, quad = lane >> 4, col = lane & 15;
    int tb  = blockIdx.x / VSLICE;
    int sl  = blockIdx.x % VSLICE;
    int t0w = tb * 512 + wid * 128;
    int v0s = sl * 1280;
    if (tid == 0) cnt = 0;

    const unsigned short* c32 = (const unsigned short*)(ws + OFF_C32);
    const uint4* W32g = (const uint4*)((const unsigned short*)(ws + OFF_W32));
    const unsigned short* WlS = (const unsigned short*)Wl4;
    float wmax = ws[OFF_WMAX];

    bf16x8 a[8];
    float thr[8][4], thrmin[8];
#pragma unroll
    for (int tt = 0; tt < 8; tt++) {
        a[tt] = *(const bf16x8*)(c32 + (t0w + tt * 16 + col) * 32 + quad * 8);
        float mn = 3.4e38f;
#pragma unroll
        for (int g = 0; g < 4; g++) {
            int t = t0w + tt * 16 + quad * 4 + g;
            float maxap = unsortable(amax1[t]);
            thr[tt][g] = maxap - (0.04f * ws[OFF_CNORM + t] * wmax + 1e-5f);
            mn = fminf(mn, thr[tt][g]);
        }
        thrmin[tt] = mn;
    }

    const f32x4 zero = {0.f, 0.f, 0.f, 0.f};

    for (int ch = 0; ch < CHUNKS; ch++) {
        __syncthreads();
        int vb = v0s + ch * 256;
#pragma unroll
        for (int i = 0; i < 4; i++)
            Wl4[tid + 256 * i] = W32g[vb * 4 + tid + 256 * i];
        __syncthreads();

        for (int vt = 0; vt < 16; vt += 2) {
            bf16x8 b0 = *(const bf16x8*)(WlS + (vt * 16 + col) * 32 + quad * 8);
            bf16x8 b1 = *(const bf16x8*)(WlS + ((vt + 1) * 16 + col) * 32 + quad * 8);
            int v0 = vb + vt * 16 + col;
#pragma unroll
            for (int tt = 0; tt < 8; tt++) {
                f32x4 d0 = __builtin_amdgcn_mfma_f32_16x16x32_bf16(a[tt], b0, zero, 0, 0, 0);
                f32x4 d1 = __builtin_amdgcn_mfma_f32_16x16x32_bf16(a[tt], b1, zero, 0, 0, 0);
                float m0 = fmaxf(d0[0], d1[0]);
                float m1 = fmaxf(d0[1], d1[1]);
                float m2 = fmaxf(d0[2], d1[2]);
                float m3 = fmaxf(d0[3], d1[3]);
                float hm = fmaxf(fmaxf(m0, m1), fmaxf(m2, m3));
                if (hm >= thrmin[tt]) {
#pragma unroll
                    for (int g = 0; g < 4; g++) {
                        unsigned t = (unsigned)(t0w + tt * 16 + quad * 4 + g);
                        if (d0[g] >= thr[tt][g]) {
                            unsigned idx = atomicAdd(&cnt, 1u);
                            if (idx < CCAP) cand[idx] = (t << 17) | (unsigned)v0;
                        }
                        if (d1[g] >= thr[tt][g]) {
                            unsigned idx = atomicAdd(&cnt, 1u);
                            if (idx < CCAP) cand[idx] = (t << 17) | (unsigned)(v0 + 16);
                        }
                    }
                }
            }
        }
    }

    __syncthreads();
    unsigned n = cnt < CCAP ? cnt : CCAP;
    const float* cmb = ws + OFF_CMB;
    for (unsigned i = tid; i < n; i += 256) {
        unsigned e = cand[i];
        int t = (int)(e >> 17);
        int v = (int)(e & 0x1FFFFu);
        const float* wr = Wio + (long long)v * 20;
        float ex = bio[v];
#pragma unroll
        for (int k = 0; k < 20; k++)
            ex = fmaf(wr[k], cmb[k * SEQ + t], ex);
        unsigned key = sortable(ex);
        unsigned long long packed =
            ((unsigned long long)key << 32) | (unsigned)(VOCAB - v);
        atomicMax(&amax[t], packed);
    }
}

// ---------------------------------------------------------------------------
// K6: unpack argmax -> float index
// ---------------------------------------------------------------------------
__global__ void k_out(const unsigned long long* __restrict__ amax,
                      float* __restrict__ out) {
    int t = blockIdx.x * blockDim.x + threadIdx.x;
    if (t >= SEQ) return;
    unsigned long long p = amax[t];
    int idx = VOCAB - (int)(p & 0xFFFFFFFFu);
    out[t] = (float)idx;
}

// ---------------------------------------------------------------------------
extern "C" void kernel_launch(void* const* d_in, const int* in_sizes, int n_in,
                              void* d_out, int out_size, void* d_ws, size_t ws_size,
                              hipStream_t stream) {
    (void)in_sizes; (void)n_in; (void)out_size; (void)ws_size;
    const int*   ix  = (const int*)d_in[0];
    const float* emb = (const float*)d_in[1];
    const float* Wih = (const float*)d_in[2];
    const float* bih = (const float*)d_in[3];
    const float* Wio = (const float*)d_in[4];
    const float* bio = (const float*)d_in[5];
    float* out = (float*)d_out;
    float* ws  = (float*)d_ws;
    unsigned long long* amax = (unsigned long long*)(ws + OFF_AMAX);
    unsigned* amax1 = (unsigned*)(ws + OFF_AMAX1);

    hipLaunchKernelGGL(k_prep,   dim3(532),           dim3(256), 0, stream, ix, emb, Wih, bih, Wio, bio, ws);
    hipLaunchKernelGGL(k_scan,   dim3(1),             dim3(128), 0, stream, Wih, ws);
    hipLaunchKernelGGL(k_pack_c, dim3(33),            dim3(256), 0, stream, ws);
    hipLaunchKernelGGL(k_max1,   dim3(TBLK * VSLICE), dim3(256), 0, stream, ws, amax1);
    hipLaunchKernelGGL(k_cand,   dim3(TBLK * VSLICE), dim3(256), 0, stream, ws, Wio, bio, amax1, amax);
    hipLaunchKernelGGL(k_out,    dim3(SEQ / 256),     dim3(256), 0, stream, amax, out);
}